// Round 6
// baseline (297.636 us; speedup 1.0000x reference)
//
#include <hip/hip_runtime.h>
#include <hip/hip_bf16.h>
#include <stdint.h>

// EdgeDecoder: out = relu(concat(zd[row], zt[col]) @ W1 + b1) @ W2 + b2
// R8: fine-grained pipeline. Layout = R2 (wave owns ALL 128 edges x 64 cols:
// A read x4, B x1 -> 25% less LDS traffic than R5's B-x4). BK=32, 16 chunks,
// ring-3 LDS buffers (74KB, 2 blocks/CU), BOTH A and B staged via gl2lds
// TWO chunks ahead; per-chunk counted vmcnt(6) waits only chunk kc+1's six
// stage ops -- kc+2's ride across two barriers (~2600cy lead >= HBM tail).
// One s_barrier per chunk. Swizzle: 4-slot XOR (slot ^= row&3), inverse on
// global source, applied on ds_read. Epilogue = R2's verified lP reduction.

typedef unsigned short u16;
typedef __attribute__((ext_vector_type(8))) short short8;
typedef __attribute__((ext_vector_type(4))) float f32x4;

#define HDIM 256
#define KDIM 512
#define BM 128     // edges per block
#define BK 32      // k-chunk
#define NCH 16     // chunks
#define NWAVE 4

__device__ __forceinline__ u16 f2bf(float f) {
  union { float f; uint32_t u; } v; v.f = f;
  uint32_t u = v.u;
  return (u16)((u + 0x7fffu + ((u >> 16) & 1u)) >> 16);   // RNE, inputs finite
}

// async global->LDS, 16B per lane; LDS dest must be wave-uniform base (+lane*16)
__device__ __forceinline__ void gl2lds16(const void* g, void* l) {
  __builtin_amdgcn_global_load_lds(
      (const __attribute__((address_space(1))) unsigned int*)g,
      (__attribute__((address_space(3))) unsigned int*)l,
      16, 0, 0);
}

// One prep kernel: blocks 0..31 do a 64x64 LDS-tiled transpose of W1
// (512x256 fp32 -> W1T 256x512 bf16, coalesced both sides); remaining blocks
// grid-stride-convert zd then zt to bf16 via float4 loads.
#define CVT_BLOCKS 4096
__global__ void prep_kernel(const float* __restrict__ zd_f,
                            const float* __restrict__ zt_f,
                            const float* __restrict__ w1,
                            u16* __restrict__ zdb, u16* __restrict__ ztb,
                            u16* __restrict__ w1t, int n4d, int n4t) {
  const int b = blockIdx.x;
  if (b < 32) {
    __shared__ float tile[64][65];
    const int k0 = (b >> 2) * 64, n0 = (b & 3) * 64;
    const int tx = threadIdx.x & 63, ty = threadIdx.x >> 6;
#pragma unroll
    for (int i = ty; i < 64; i += 4)
      tile[i][tx] = w1[(size_t)(k0 + i) * HDIM + n0 + tx];   // coalesced 256B
    __syncthreads();
#pragma unroll
    for (int i = ty; i < 64; i += 4)
      w1t[(size_t)(n0 + i) * KDIM + k0 + tx] = f2bf(tile[tx][i]);  // coalesced
  } else {
    const int idx = (b - 32) * 256 + threadIdx.x;
    const int stride = CVT_BLOCKS * 256;
    for (int i = idx; i < n4d; i += stride) {
      float4 v = ((const float4*)zd_f)[i];
      ushort4 o; o.x = f2bf(v.x); o.y = f2bf(v.y); o.z = f2bf(v.z); o.w = f2bf(v.w);
      ((ushort4*)zdb)[i] = o;
    }
    for (int i = idx; i < n4t; i += stride) {
      float4 v = ((const float4*)zt_f)[i];
      ushort4 o; o.x = f2bf(v.x); o.y = f2bf(v.y); o.z = f2bf(v.z); o.w = f2bf(v.w);
      ((ushort4*)ztb)[i] = o;
    }
  }
}

// Main fused kernel. Block = 256 thr (4 waves). Tile: 128 edges x 256 cols;
// wave w owns cols [w*64, w*64+64) x ALL 128 edges (acc[8][4]).
// 16 chunks of BK=32 (0-7 zd[row], 8-15 zt[col]). Ring-3 LDS, stage kc+2.
__global__ __launch_bounds__(256, 2) void edge_mlp_kernel(
    const u16* __restrict__ zd, const u16* __restrict__ zt,
    const int* __restrict__ row, const int* __restrict__ col,
    const u16* __restrict__ w1t, const float* __restrict__ b1,
    const float* __restrict__ w2, const float* __restrict__ b2,
    float* __restrict__ out, int E) {
  __shared__ u16 lA[3][BM * BK];    // 3 x 8KB  [edge][k], 4x16B-slot swizzled
  __shared__ u16 lB[3][HDIM * BK];  // 3 x 16KB [n][k],    4x16B-slot swizzled
  __shared__ float lP[NWAVE * BM];  // 2KB per-wave layer-2 partials

  const int tid   = threadIdx.x;
  const int wid   = tid >> 6;                      // 0..3
  const int lane  = tid & 63;
  const int e0    = blockIdx.x * BM;
  const int le    = lane >> 2;                     // staged row within 16-group
  const int ls    = lane & 3;                      // 16B slot within 64B row
  const int sp    = (ls ^ (le & 3)) * 8;           // inverse-swizzled src piece
  const int colid = lane & 15;
  const int quad  = lane >> 4;
  const int cq    = colid & 3;                     // read-side swizzle key

  // A-staging: wave w stages edges [w*32, +32) in 2 issues of 16 rows.
  uint32_t offD[2], offT[2];
#pragma unroll
  for (int t = 0; t < 2; ++t) {
    int ge = min(e0 + wid * 32 + t * 16 + le, E - 1);
    offD[t] = (uint32_t)row[ge] * HDIM;
    offT[t] = (uint32_t)col[ge] * HDIM;
  }
  // B-staging: wave w stages n-rows [w*64, +64) in 4 issues of 16 rows.
  const u16* pB = w1t + (uint32_t)(wid * 64 + le) * KDIM + sp;

  f32x4 acc[8][4];
#pragma unroll
  for (int i = 0; i < 8; ++i)
#pragma unroll
    for (int j = 0; j < 4; ++j) acc[i][j] = f32x4{0.f, 0.f, 0.f, 0.f};

  // Stage chunk kc into ring buffer buf: 2 A-issues + 4 B-issues = 6 vmem.
  auto stage = [&](int kc, int buf) {
    const u16* zb = (kc < 8) ? zd : zt;
    const uint32_t* offs = (kc < 8) ? offD : offT;
    const int koff = (kc & 7) * BK;
#pragma unroll
    for (int t = 0; t < 2; ++t)
      gl2lds16(zb + offs[t] + koff + sp,
               &lA[buf][(wid * 32 + t * 16) * BK]);
#pragma unroll
    for (int t = 0; t < 4; ++t)
      gl2lds16(pB + (size_t)(t * 16) * KDIM + kc * BK,
               &lB[buf][(wid * 64 + t * 16) * BK]);
  };

  // Prologue: stage chunks 0 and 1; wait for chunk 0 (oldest 6).
  stage(0, 0);
  stage(1, 1);
  asm volatile("s_waitcnt vmcnt(6)" ::: "memory");
  __builtin_amdgcn_s_barrier();

#pragma unroll
  for (int kc = 0; kc < NCH; ++kc) {
    const int cur = kc % 3;
    if (kc < NCH - 2) stage(kc + 2, (kc + 2) % 3);

    // Fragments: aF over all 128 edges, bF over this wave's 64 cols.
    // row r, k-slot quad -> swizzled slot (quad ^ (r&3)); r&3 == colid&3.
    short8 aF[8], bF[4];
#pragma unroll
    for (int rt = 0; rt < 8; ++rt)
      aF[rt] = *(const short8*)
          &lA[cur][(rt * 16 + colid) * BK + ((quad ^ cq) * 8)];
#pragma unroll
    for (int ct = 0; ct < 4; ++ct)
      bF[ct] = *(const short8*)
          &lB[cur][(wid * 64 + ct * 16 + colid) * BK + ((quad ^ cq) * 8)];

    __builtin_amdgcn_s_setprio(1);
#pragma unroll
    for (int rt = 0; rt < 8; ++rt)
#pragma unroll
      for (int ct = 0; ct < 4; ++ct)
        acc[rt][ct] = __builtin_amdgcn_mfma_f32_16x16x32_bf16(
            aF[rt], bF[ct], acc[rt][ct], 0, 0, 0);
    __builtin_amdgcn_s_setprio(0);

    if (kc < NCH - 1) {
      // Counted drain: wait chunk kc+1's 6 stages (kc+2's 6 stay in flight
      // across the barrier; their wait is the next chunk's counted drain).
      if (kc < NCH - 2)
        asm volatile("s_waitcnt vmcnt(6)" ::: "memory");
      else
        asm volatile("s_waitcnt vmcnt(0)" ::: "memory");
      __builtin_amdgcn_s_barrier();
    }
  }

  // Epilogue: h = relu(acc + b1[n]); partial[e] = sum_n h*W2[n] (fp32)
  // C/D layout: n = wid*64 + ct*16 + colid, e = rt*16 + quad*4 + j
  float b1v[4], w2v[4];
#pragma unroll
  for (int ct = 0; ct < 4; ++ct) {
    int n = wid * 64 + ct * 16 + colid;
    b1v[ct] = b1[n];
    w2v[ct] = w2[n];
  }
#pragma unroll
  for (int rt = 0; rt < 8; ++rt)
#pragma unroll
    for (int j = 0; j < 4; ++j) {
      float s = 0.f;
#pragma unroll
      for (int ct = 0; ct < 4; ++ct)
        s += fmaxf(acc[rt][ct][j] + b1v[ct], 0.f) * w2v[ct];
#pragma unroll
      for (int off = 8; off >= 1; off >>= 1)
        s += __shfl_xor(s, off, 16);             // sum over n within quad-row
      if (colid == 0)
        lP[wid * BM + rt * 16 + quad * 4 + j] = s;
    }
  __syncthreads();
  if (tid < BM) {
    int ge = e0 + tid;
    if (ge < E)
      out[ge] = lP[tid] + lP[BM + tid] + lP[2 * BM + tid] + lP[3 * BM + tid]
                + b2[0];
  }
}

// Correct-but-slow fp32 fallback (only if ws_size < 36.2MB): 16 edges/block.
__global__ void fallback_kernel(
    const float* __restrict__ zd, const float* __restrict__ zt,
    const int* __restrict__ row, const int* __restrict__ col,
    const float* __restrict__ W1, const float* __restrict__ b1,
    const float* __restrict__ W2, const float* __restrict__ b2,
    float* __restrict__ out, int E) {
  __shared__ float zc[16][512];
  __shared__ float red[4][16];
  const int e0 = blockIdx.x * 16;
  const int tid = threadIdx.x;
  for (int i = tid; i < 16 * 512; i += 256) {
    int e = i >> 9, k = i & 511;
    int ge = min(e0 + e, E - 1);
    zc[e][k] = (k < HDIM) ? zd[(size_t)row[ge] * HDIM + k]
                          : zt[(size_t)col[ge] * HDIM + (k - HDIM)];
  }
  __syncthreads();
  float acc[16];
#pragma unroll
  for (int e = 0; e < 16; ++e) acc[e] = 0.f;
  for (int k = 0; k < KDIM; ++k) {
    float w = W1[k * HDIM + tid];
#pragma unroll
    for (int e = 0; e < 16; ++e) acc[e] += zc[e][k] * w;
  }
  float wv = W2[tid], bv = b1[tid];
  const int lane = tid & 63, wid = tid >> 6;
#pragma unroll
  for (int e = 0; e < 16; ++e) {
    float pv = fmaxf(acc[e] + bv, 0.f) * wv;
#pragma unroll
    for (int off = 32; off >= 1; off >>= 1) pv += __shfl_down(pv, off, 64);
    if (lane == 0) red[wid][e] = pv;
  }
  __syncthreads();
  if (tid < 16) {
    int ge = e0 + tid;
    if (ge < E)
      out[ge] = red[0][tid] + red[1][tid] + red[2][tid] + red[3][tid] + b2[0];
  }
}

extern "C" void kernel_launch(void* const* d_in, const int* in_sizes, int n_in,
                              void* d_out, int out_size, void* d_ws, size_t ws_size,
                              hipStream_t stream) {
  const float* zd_f = (const float*)d_in[0];
  const float* zt_f = (const float*)d_in[1];
  const int*   row  = (const int*)d_in[2];
  const int*   col  = (const int*)d_in[3];
  const float* W1   = (const float*)d_in[4];
  const float* b1   = (const float*)d_in[5];
  const float* W2   = (const float*)d_in[6];
  const float* b2   = (const float*)d_in[7];
  float* out = (float*)d_out;

  const int E  = in_sizes[2];            // 500000
  const int ND = in_sizes[0] / HDIM;     // 50000
  const int NT = in_sizes[1] / HDIM;     // 20000

  size_t off_w1t = 0;                                    // 256KB
  size_t off_zd  = (size_t)KDIM * HDIM * sizeof(u16);
  size_t off_zt  = off_zd + (size_t)ND * HDIM * sizeof(u16);
  size_t need    = off_zt + (size_t)NT * HDIM * sizeof(u16);  // ~36.1MB

  if (ws_size >= need) {
    u16* w1t = (u16*)((char*)d_ws + off_w1t);
    u16* zdb = (u16*)((char*)d_ws + off_zd);
    u16* ztb = (u16*)((char*)d_ws + off_zt);
    int n4d = ND * HDIM / 4, n4t = NT * HDIM / 4;
    prep_kernel<<<32 + CVT_BLOCKS, 256, 0, stream>>>(zd_f, zt_f, W1,
                                                     zdb, ztb, w1t, n4d, n4t);
    edge_mlp_kernel<<<(E + BM - 1) / BM, 256, 0, stream>>>(
        zdb, ztb, row, col, w1t, b1, W2, b2, out, E);
  } else {
    fallback_kernel<<<(E + 15) / 16, 256, 0, stream>>>(
        zd_f, zt_f, row, col, W1, b1, W2, b2, out, E);
  }
}

// Round 7
// 278.915 us; speedup vs baseline: 1.0671x; 1.0671x over previous
//
#include <hip/hip_runtime.h>
#include <hip/hip_bf16.h>
#include <stdint.h>

// EdgeDecoder: out = relu(concat(zd[row], zt[col]) @ W1 + b1) @ W2 + b2
// R9: R2's low-LDS-traffic layout (wave = ALL 128 edges x 64 cols -> 24
// ds_read_b128/wave/chunk, each bF feeds 8 MFMAs) + R5's overlap structure.
// BK=64 restored (R8 lesson: the 0-conflict swizzle needs 128B rows; BK=32's
// 64B rows alias banks 4-way -> 1.2e7 conflicts). lA dbuf 2x16KB, lB single
// 32KB (66KB total -> 2 blocks/CU). Per chunk: read all 8 bF -> lgkmcnt(0)
// + barrier1 (lB free) -> stage A(kc+1)->lA[nxt] then B(kc+1)->lB (12
// gl2lds overlap the MFMA phase) -> aF reads + 64 MFMA -> vmcnt(0) +
// barrier2 (drain covered by compute). Fragments/swizzle/epilogue are R2's
// verified bytes.

typedef unsigned short u16;
typedef __attribute__((ext_vector_type(8))) short short8;
typedef __attribute__((ext_vector_type(4))) float f32x4;

#define HDIM 256
#define KDIM 512
#define BM 128     // edges per block
#define BK 64      // k-chunk
#define NWAVE 4

__device__ __forceinline__ u16 f2bf(float f) {
  union { float f; uint32_t u; } v; v.f = f;
  uint32_t u = v.u;
  return (u16)((u + 0x7fffu + ((u >> 16) & 1u)) >> 16);   // RNE, inputs finite
}

// async global->LDS, 16B per lane; LDS dest must be wave-uniform base (+lane*16)
__device__ __forceinline__ void gl2lds16(const void* g, void* l) {
  __builtin_amdgcn_global_load_lds(
      (const __attribute__((address_space(1))) unsigned int*)g,
      (__attribute__((address_space(3))) unsigned int*)l,
      16, 0, 0);
}

// One prep kernel: blocks 0..31 do a 64x64 LDS-tiled transpose of W1
// (512x256 fp32 -> W1T 256x512 bf16, coalesced both sides); remaining blocks
// grid-stride-convert zd then zt to bf16 via float4 loads.
#define CVT_BLOCKS 4096
__global__ void prep_kernel(const float* __restrict__ zd_f,
                            const float* __restrict__ zt_f,
                            const float* __restrict__ w1,
                            u16* __restrict__ zdb, u16* __restrict__ ztb,
                            u16* __restrict__ w1t, int n4d, int n4t) {
  const int b = blockIdx.x;
  if (b < 32) {
    __shared__ float tile[64][65];
    const int k0 = (b >> 2) * 64, n0 = (b & 3) * 64;
    const int tx = threadIdx.x & 63, ty = threadIdx.x >> 6;
#pragma unroll
    for (int i = ty; i < 64; i += 4)
      tile[i][tx] = w1[(size_t)(k0 + i) * HDIM + n0 + tx];   // coalesced 256B
    __syncthreads();
#pragma unroll
    for (int i = ty; i < 64; i += 4)
      w1t[(size_t)(n0 + i) * KDIM + k0 + tx] = f2bf(tile[tx][i]);  // coalesced
  } else {
    const int idx = (b - 32) * 256 + threadIdx.x;
    const int stride = CVT_BLOCKS * 256;
    for (int i = idx; i < n4d; i += stride) {
      float4 v = ((const float4*)zd_f)[i];
      ushort4 o; o.x = f2bf(v.x); o.y = f2bf(v.y); o.z = f2bf(v.z); o.w = f2bf(v.w);
      ((ushort4*)zdb)[i] = o;
    }
    for (int i = idx; i < n4t; i += stride) {
      float4 v = ((const float4*)zt_f)[i];
      ushort4 o; o.x = f2bf(v.x); o.y = f2bf(v.y); o.z = f2bf(v.z); o.w = f2bf(v.w);
      ((ushort4*)ztb)[i] = o;
    }
  }
}

// Main fused kernel. Block = 256 thr (4 waves). Tile: 128 edges x 256 cols,
// wave w owns cols [w*64, +64) across ALL 128 edges (acc[8][4]).
// K-loop: 8 chunks of BK=64 (0-3 zd[row], 4-7 zt[col]).
__global__ __launch_bounds__(256, 2) void edge_mlp_kernel(
    const u16* __restrict__ zd, const u16* __restrict__ zt,
    const int* __restrict__ row, const int* __restrict__ col,
    const u16* __restrict__ w1t, const float* __restrict__ b1,
    const float* __restrict__ w2, const float* __restrict__ b2,
    float* __restrict__ out, int E) {
  __shared__ u16 lA[2][BM * BK];   // 2 x 16KB [edge][k], 16B-slot XOR-swizzled
  __shared__ u16 lB[HDIM * BK];    // 32KB single-buf [n][k], same swizzle
  __shared__ float lP[NWAVE * BM]; // 2KB per-wave layer-2 partials

  const int tid   = threadIdx.x;
  const int wid   = tid >> 6;                      // 0..3
  const int lane  = tid & 63;
  const int e0    = blockIdx.x * BM;
  const int r8    = lane >> 3;                     // row-in-8-group per issue
  const int slog  = ((lane & 7) ^ (r8 & 7)) * 8;   // swizzled 16B-slot offset
  const int colid = lane & 15;
  const int quad  = lane >> 4;
  const int csw   = colid & 7;     // read-side swizzle key (row&7 == colid&7)

  // A-staging: wave w stages edges [w*32, +32) in 4 issues of 8 rows.
  uint32_t offD[4], offT[4];
#pragma unroll
  for (int t = 0; t < 4; ++t) {
    int ge = min(e0 + wid * 32 + r8 + 8 * t, E - 1);
    offD[t] = (uint32_t)row[ge] * HDIM;
    offT[t] = (uint32_t)col[ge] * HDIM;
  }
  // B-staging: wave w stages its n-rows [w*64, +64) in 8 issues of 8 rows.
  const u16* pB = w1t + (uint32_t)(wid * 64 + r8) * KDIM + slog;

  u16* lAw0 = &lA[0][(wid * 32) * BK];   // wave-uniform LDS bases
  u16* lAw1 = &lA[1][(wid * 32) * BK];
  u16* lBw  = &lB[(wid * 64) * BK];

  f32x4 acc[8][4];
#pragma unroll
  for (int i = 0; i < 8; ++i)
#pragma unroll
    for (int j = 0; j < 4; ++j) acc[i][j] = f32x4{0.f, 0.f, 0.f, 0.f};

  auto stageA = [&](int kc, int buf) {
    const u16* zb = (kc < 4) ? zd : zt;
    const uint32_t* offs = (kc < 4) ? offD : offT;
    const int koff = (kc & 3) * BK;
    u16* dA = buf ? lAw1 : lAw0;
#pragma unroll
    for (int t = 0; t < 4; ++t)
      gl2lds16(zb + offs[t] + koff + slog, dA + (8 * t) * BK);
  };
  auto stageB = [&](int kc) {
#pragma unroll
    for (int j = 0; j < 8; ++j)
      gl2lds16(pB + (size_t)j * 8 * KDIM + kc * BK, lBw + j * 8 * BK);
  };

  // Prologue: stage chunk 0 (A->buf0, B), drain, barrier.
  stageA(0, 0);
  stageB(0);
  asm volatile("s_waitcnt vmcnt(0)" ::: "memory");
  __builtin_amdgcn_s_barrier();

#pragma unroll
  for (int kc = 0; kc < 8; ++kc) {
    const int cur = kc & 1;

    // Read ALL bF for this chunk (both s-phases) from single-buffered lB.
    short8 bF[2][4];
#pragma unroll
    for (int s = 0; s < 2; ++s) {
      const int sl = s * 4 + quad;
#pragma unroll
      for (int ct = 0; ct < 4; ++ct)
        bF[s][ct] = *(const short8*)
            &lB[(wid * 64 + ct * 16 + colid) * BK + ((sl ^ csw) * 8)];
    }
    asm volatile("s_waitcnt lgkmcnt(0)" ::: "memory");  // bF in regs
    __builtin_amdgcn_s_barrier();                       // lB free for restage
    __builtin_amdgcn_sched_barrier(0);                  // nothing hoists above

    if (kc < 7) {
      stageA(kc + 1, cur ^ 1);   // latency-random gathers first
      stageB(kc + 1);            // L2-hot weight rows
    }

    // Compute chunk kc: aF from dbuf'd lA[cur] (untouched by staging) + bF.
    const u16* A = cur ? (lA[1]) : (lA[0]);
#pragma unroll
    for (int s = 0; s < 2; ++s) {
      const int sl = s * 4 + quad;
      short8 aF[8];
#pragma unroll
      for (int rt = 0; rt < 8; ++rt)
        aF[rt] = *(const short8*)&A[(rt * 16 + colid) * BK + ((sl ^ csw) * 8)];
      __builtin_amdgcn_s_setprio(1);
#pragma unroll
      for (int rt = 0; rt < 8; ++rt)
#pragma unroll
        for (int ct = 0; ct < 4; ++ct)
          acc[rt][ct] = __builtin_amdgcn_mfma_f32_16x16x32_bf16(
              aF[rt], bF[s][ct], acc[rt][ct], 0, 0, 0);
      __builtin_amdgcn_s_setprio(0);
    }

    if (kc < 7) {
      // Drain this chunk's stages (covered by the MFMA phase above).
      asm volatile("s_waitcnt vmcnt(0)" ::: "memory");
      __builtin_amdgcn_s_barrier();
    }
  }

  // Epilogue: h = relu(acc + b1[n]); partial[e] = sum_n h*W2[n] (fp32)
  // C/D layout: n = wid*64 + ct*16 + colid, e = rt*16 + quad*4 + j
  float b1v[4], w2v[4];
#pragma unroll
  for (int ct = 0; ct < 4; ++ct) {
    int n = wid * 64 + ct * 16 + colid;
    b1v[ct] = b1[n];
    w2v[ct] = w2[n];
  }
#pragma unroll
  for (int rt = 0; rt < 8; ++rt)
#pragma unroll
    for (int j = 0; j < 4; ++j) {
      float s = 0.f;
#pragma unroll
      for (int ct = 0; ct < 4; ++ct)
        s += fmaxf(acc[rt][ct][j] + b1v[ct], 0.f) * w2v[ct];
#pragma unroll
      for (int off = 8; off >= 1; off >>= 1)
        s += __shfl_xor(s, off, 16);             // sum over n within quad-row
      if (colid == 0)
        lP[wid * BM + rt * 16 + quad * 4 + j] = s;
    }
  __syncthreads();
  if (tid < BM) {
    int ge = e0 + tid;
    if (ge < E)
      out[ge] = lP[tid] + lP[BM + tid] + lP[2 * BM + tid] + lP[3 * BM + tid]
                + b2[0];
  }
}

// Correct-but-slow fp32 fallback (only if ws_size < 36.2MB): 16 edges/block.
__global__ void fallback_kernel(
    const float* __restrict__ zd, const float* __restrict__ zt,
    const int* __restrict__ row, const int* __restrict__ col,
    const float* __restrict__ W1, const float* __restrict__ b1,
    const float* __restrict__ W2, const float* __restrict__ b2,
    float* __restrict__ out, int E) {
  __shared__ float zc[16][512];
  __shared__ float red[4][16];
  const int e0 = blockIdx.x * 16;
  const int tid = threadIdx.x;
  for (int i = tid; i < 16 * 512; i += 256) {
    int e = i >> 9, k = i & 511;
    int ge = min(e0 + e, E - 1);
    zc[e][k] = (k < HDIM) ? zd[(size_t)row[ge] * HDIM + k]
                          : zt[(size_t)col[ge] * HDIM + (k - HDIM)];
  }
  __syncthreads();
  float acc[16];
#pragma unroll
  for (int e = 0; e < 16; ++e) acc[e] = 0.f;
  for (int k = 0; k < KDIM; ++k) {
    float w = W1[k * HDIM + tid];
#pragma unroll
    for (int e = 0; e < 16; ++e) acc[e] += zc[e][k] * w;
  }
  float wv = W2[tid], bv = b1[tid];
  const int lane = tid & 63, wid = tid >> 6;
#pragma unroll
  for (int e = 0; e < 16; ++e) {
    float pv = fmaxf(acc[e] + bv, 0.f) * wv;
#pragma unroll
    for (int off = 32; off >= 1; off >>= 1) pv += __shfl_down(pv, off, 64);
    if (lane == 0) red[wid][e] = pv;
  }
  __syncthreads();
  if (tid < 16) {
    int ge = e0 + tid;
    if (ge < E)
      out[ge] = red[0][tid] + red[1][tid] + red[2][tid] + red[3][tid] + b2[0];
  }
}

extern "C" void kernel_launch(void* const* d_in, const int* in_sizes, int n_in,
                              void* d_out, int out_size, void* d_ws, size_t ws_size,
                              hipStream_t stream) {
  const float* zd_f = (const float*)d_in[0];
  const float* zt_f = (const float*)d_in[1];
  const int*   row  = (const int*)d_in[2];
  const int*   col  = (const int*)d_in[3];
  const float* W1   = (const float*)d_in[4];
  const float* b1   = (const float*)d_in[5];
  const float* W2   = (const float*)d_in[6];
  const float* b2   = (const float*)d_in[7];
  float* out = (float*)d_out;

  const int E  = in_sizes[2];            // 500000
  const int ND = in_sizes[0] / HDIM;     // 50000
  const int NT = in_sizes[1] / HDIM;     // 20000

  size_t off_w1t = 0;                                    // 256KB
  size_t off_zd  = (size_t)KDIM * HDIM * sizeof(u16);
  size_t off_zt  = off_zd + (size_t)ND * HDIM * sizeof(u16);
  size_t need    = off_zt + (size_t)NT * HDIM * sizeof(u16);  // ~36.1MB

  if (ws_size >= need) {
    u16* w1t = (u16*)((char*)d_ws + off_w1t);
    u16* zdb = (u16*)((char*)d_ws + off_zd);
    u16* ztb = (u16*)((char*)d_ws + off_zt);
    int n4d = ND * HDIM / 4, n4t = NT * HDIM / 4;
    prep_kernel<<<32 + CVT_BLOCKS, 256, 0, stream>>>(zd_f, zt_f, W1,
                                                     zdb, ztb, w1t, n4d, n4t);
    edge_mlp_kernel<<<(E + BM - 1) / BM, 256, 0, stream>>>(
        zdb, ztb, row, col, w1t, b1, W2, b2, out, E);
  } else {
    fallback_kernel<<<(E + 15) / 16, 256, 0, stream>>>(
        zd_f, zt_f, row, col, W1, b1, W2, b2, out, E);
  }
}

// Round 8
// 275.119 us; speedup vs baseline: 1.0818x; 1.0138x over previous
//
#include <hip/hip_runtime.h>
#include <hip/hip_bf16.h>
#include <stdint.h>

// EdgeDecoder: out = relu(concat(zd[row], zt[col]) @ W1 + b1) @ W2 + b2
// R10: occupancy attack. All R3-R9 variants pinned at 2 waves/SIMD (acc[2][16]
// =128 AGPR + ~120 VGPR = 248 regs) -> MfmaUtil ~34% regardless of schedule.
// Halve the accumulator: wave owns 32 edges x 128 cols (acc[2][8] = 64 AGPR,
// ~160 total regs -> 3 waves/SIMD per m97 precedent). Cols split across TWO
// blocks per 128-edge group; partials combined via atomicAdd into memset-0
// output (b2 added by half 0). Block = 256 thr, LDS = B-dbuf 2x16KB only
// (128 rows x BK=64: verified 0-conflict swizzle) -> 3 blocks/CU. Chunk
// structure = R5's best: stage B(kc+1) gl2lds, prefetch A(kc+1) direct to
// VGPR, compute 32 MFMA, one vmcnt(0)+barrier.

typedef unsigned short u16;
typedef __attribute__((ext_vector_type(8))) short short8;
typedef __attribute__((ext_vector_type(4))) float f32x4;

#define HDIM 256
#define KDIM 512
#define EG 128     // edges per group (two blocks share a group)
#define BK 64      // k-chunk

__device__ __forceinline__ u16 f2bf(float f) {
  union { float f; uint32_t u; } v; v.f = f;
  uint32_t u = v.u;
  return (u16)((u + 0x7fffu + ((u >> 16) & 1u)) >> 16);   // RNE, inputs finite
}

// async global->LDS, 16B per lane; LDS dest must be wave-uniform base (+lane*16)
__device__ __forceinline__ void gl2lds16(const void* g, void* l) {
  __builtin_amdgcn_global_load_lds(
      (const __attribute__((address_space(1))) unsigned int*)g,
      (__attribute__((address_space(3))) unsigned int*)l,
      16, 0, 0);
}

// One prep kernel: blocks 0..31 do a 64x64 LDS-tiled transpose of W1
// (512x256 fp32 -> W1T 256x512 bf16, coalesced both sides); remaining blocks
// grid-stride-convert zd then zt to bf16 via float4 loads.
#define CVT_BLOCKS 4096
__global__ void prep_kernel(const float* __restrict__ zd_f,
                            const float* __restrict__ zt_f,
                            const float* __restrict__ w1,
                            u16* __restrict__ zdb, u16* __restrict__ ztb,
                            u16* __restrict__ w1t, int n4d, int n4t) {
  const int b = blockIdx.x;
  if (b < 32) {
    __shared__ float tile[64][65];
    const int k0 = (b >> 2) * 64, n0 = (b & 3) * 64;
    const int tx = threadIdx.x & 63, ty = threadIdx.x >> 6;
#pragma unroll
    for (int i = ty; i < 64; i += 4)
      tile[i][tx] = w1[(size_t)(k0 + i) * HDIM + n0 + tx];   // coalesced 256B
    __syncthreads();
#pragma unroll
    for (int i = ty; i < 64; i += 4)
      w1t[(size_t)(n0 + i) * KDIM + k0 + tx] = f2bf(tile[tx][i]);  // coalesced
  } else {
    const int idx = (b - 32) * 256 + threadIdx.x;
    const int stride = CVT_BLOCKS * 256;
    for (int i = idx; i < n4d; i += stride) {
      float4 v = ((const float4*)zd_f)[i];
      ushort4 o; o.x = f2bf(v.x); o.y = f2bf(v.y); o.z = f2bf(v.z); o.w = f2bf(v.w);
      ((ushort4*)zdb)[i] = o;
    }
    for (int i = idx; i < n4t; i += stride) {
      float4 v = ((const float4*)zt_f)[i];
      ushort4 o; o.x = f2bf(v.x); o.y = f2bf(v.y); o.z = f2bf(v.z); o.w = f2bf(v.w);
      ((ushort4*)ztb)[i] = o;
    }
  }
}

// Main fused kernel. Block = 256 thr (4 waves). Block (g,h): edges
// [g*128,+128), cols [h*128,+128). Wave w: edges [g*128+w*32,+32) x the
// half's 128 cols -> acc[2][8]. K-loop: 8 chunks BK=64 (0-3 zd, 4-7 zt).
// Output: atomicAdd partials (out pre-zeroed); half 0 adds b2.
__global__ __launch_bounds__(256, 3) void edge_mlp_kernel(
    const u16* __restrict__ zd, const u16* __restrict__ zt,
    const int* __restrict__ row, const int* __restrict__ col,
    const u16* __restrict__ w1t, const float* __restrict__ b1,
    const float* __restrict__ w2, const float* __restrict__ b2,
    float* __restrict__ out, int E) {
  __shared__ u16 lB[2][128 * BK];  // 2 x 16KB [n_local][k], XOR-swizzled

  const int tid   = threadIdx.x;
  const int wid   = tid >> 6;                      // 0..3
  const int lane  = tid & 63;
  const int g     = blockIdx.x >> 1;               // edge group
  const int h     = blockIdx.x & 1;                // col half
  const int e0    = g * EG;
  const int n0    = h * 128;                       // col base
  const int r8    = lane >> 3;                     // row-in-8-group per issue
  const int slog  = ((lane & 7) ^ (r8 & 7)) * 8;   // swizzled 16B-slot offset
  const int colid = lane & 15;
  const int quad  = lane >> 4;
  const int csw   = colid & 7;     // read-side swizzle key (row&7 == colid&7)

  // B-staging: wave w stages n-rows [n0 + w*32, +32) in 4 issues of 8 rows.
  const u16* pB = w1t + (uint32_t)(n0 + wid * 32 + r8) * KDIM + slog;
  u16* lBw0 = &lB[0][(wid * 32) * BK];
  u16* lBw1 = &lB[1][(wid * 32) * BK];

  // Per-lane A row offsets: lane colid picks edge rt*16+colid of this wave.
  uint32_t offD2[2], offT2[2];
#pragma unroll
  for (int rt = 0; rt < 2; ++rt) {
    int ge = min(e0 + wid * 32 + rt * 16 + colid, E - 1);
    offD2[rt] = (uint32_t)row[ge] * HDIM;
    offT2[rt] = (uint32_t)col[ge] * HDIM;
  }

  f32x4 acc[2][8];
#pragma unroll
  for (int i = 0; i < 2; ++i)
#pragma unroll
    for (int j = 0; j < 8; ++j) acc[i][j] = f32x4{0.f, 0.f, 0.f, 0.f};

  short8 aR[2][2][2];   // [kc&1][rt][s] — static-indexed (K-loop fully unrolled)

  // Prologue: stage B(0), load A(0) fragments.
#pragma unroll
  for (int t = 0; t < 4; ++t)
    gl2lds16(pB + (size_t)t * 8 * KDIM, lBw0 + t * 8 * BK);
#pragma unroll
  for (int rt = 0; rt < 2; ++rt)
#pragma unroll
    for (int s = 0; s < 2; ++s)
      aR[0][rt][s] = *(const short8*)(zd + offD2[rt] + s * 32 + quad * 8);
  asm volatile("s_waitcnt vmcnt(0)" ::: "memory");
  __builtin_amdgcn_s_barrier();

#pragma unroll
  for (int kc = 0; kc < 8; ++kc) {
    const int cur = kc & 1, nxt = cur ^ 1;
    if (kc < 7) {
      const int kn = kc + 1;
#pragma unroll
      for (int t = 0; t < 4; ++t)
        gl2lds16(pB + (size_t)t * 8 * KDIM + kn * BK,
                 (nxt ? lBw1 : lBw0) + t * 8 * BK);
      const u16* zb = (kn < 4) ? zd : zt;                     // static
      const uint32_t* offs = (kn < 4) ? offD2 : offT2;        // static
      const int koffn = (kn & 3) * BK;
#pragma unroll
      for (int rt = 0; rt < 2; ++rt)
#pragma unroll
        for (int s = 0; s < 2; ++s)
          aR[nxt][rt][s] =
              *(const short8*)(zb + offs[rt] + koffn + s * 32 + quad * 8);
    }
    // Compute chunk kc: aR[cur] (regs) x lB[cur] (LDS), 32 MFMA.
#pragma unroll
    for (int s = 0; s < 2; ++s) {
      const int sl = s * 4 + quad;                 // logical 16B slot
      __builtin_amdgcn_s_setprio(1);
#pragma unroll
      for (int ct = 0; ct < 8; ++ct) {
        short8 bF = *(const short8*)
            &lB[cur][(ct * 16 + colid) * BK + ((sl ^ csw) * 8)];
        acc[0][ct] = __builtin_amdgcn_mfma_f32_16x16x32_bf16(
            aR[cur][0][s], bF, acc[0][ct], 0, 0, 0);
        acc[1][ct] = __builtin_amdgcn_mfma_f32_16x16x32_bf16(
            aR[cur][1][s], bF, acc[1][ct], 0, 0, 0);
      }
      __builtin_amdgcn_s_setprio(0);
    }
    if (kc < 7) {
      // Drain next-chunk stages/loads (covered by compute) + barrier.
      asm volatile("s_waitcnt vmcnt(0)" ::: "memory");
      __builtin_amdgcn_s_barrier();
    }
  }

  // Epilogue (wave-local): partial[e] = sum over this half's 128 cols of
  // relu(acc + b1[n]) * W2[n]; atomicAdd into out (pre-zeroed).
  // C/D layout: n = n0 + ct*16 + colid, e = e0 + wid*32 + rt*16 + quad*4 + j.
  float b1v[8], w2v[8];
#pragma unroll
  for (int ct = 0; ct < 8; ++ct) {
    int n = n0 + ct * 16 + colid;
    b1v[ct] = b1[n];
    w2v[ct] = w2[n];
  }
  const float badd = (h == 0) ? b2[0] : 0.f;
#pragma unroll
  for (int rt = 0; rt < 2; ++rt)
#pragma unroll
    for (int j = 0; j < 4; ++j) {
      float s = 0.f;
#pragma unroll
      for (int ct = 0; ct < 8; ++ct)
        s += fmaxf(acc[rt][ct][j] + b1v[ct], 0.f) * w2v[ct];
#pragma unroll
      for (int off = 8; off >= 1; off >>= 1)
        s += __shfl_xor(s, off, 16);               // sum over the 16 colids
      if (colid == 0) {
        int ge = e0 + wid * 32 + rt * 16 + quad * 4 + j;
        if (ge < E) atomicAdd(&out[ge], s + badd);
      }
    }
}

// Correct-but-slow fp32 fallback (only if ws_size < 36.2MB): 16 edges/block.
__global__ void fallback_kernel(
    const float* __restrict__ zd, const float* __restrict__ zt,
    const int* __restrict__ row, const int* __restrict__ col,
    const float* __restrict__ W1, const float* __restrict__ b1,
    const float* __restrict__ W2, const float* __restrict__ b2,
    float* __restrict__ out, int E) {
  __shared__ float zc[16][512];
  __shared__ float red[4][16];
  const int e0 = blockIdx.x * 16;
  const int tid = threadIdx.x;
  for (int i = tid; i < 16 * 512; i += 256) {
    int e = i >> 9, k = i & 511;
    int ge = min(e0 + e, E - 1);
    zc[e][k] = (k < HDIM) ? zd[(size_t)row[ge] * HDIM + k]
                          : zt[(size_t)col[ge] * HDIM + (k - HDIM)];
  }
  __syncthreads();
  float acc[16];
#pragma unroll
  for (int e = 0; e < 16; ++e) acc[e] = 0.f;
  for (int k = 0; k < KDIM; ++k) {
    float w = W1[k * HDIM + tid];
#pragma unroll
    for (int e = 0; e < 16; ++e) acc[e] += zc[e][k] * w;
  }
  float wv = W2[tid], bv = b1[tid];
  const int lane = tid & 63, wid = tid >> 6;
#pragma unroll
  for (int e = 0; e < 16; ++e) {
    float pv = fmaxf(acc[e] + bv, 0.f) * wv;
#pragma unroll
    for (int off = 32; off >= 1; off >>= 1) pv += __shfl_down(pv, off, 64);
    if (lane == 0) red[wid][e] = pv;
  }
  __syncthreads();
  if (tid < 16) {
    int ge = e0 + tid;
    if (ge < E)
      out[ge] = red[0][tid] + red[1][tid] + red[2][tid] + red[3][tid] + b2[0];
  }
}

extern "C" void kernel_launch(void* const* d_in, const int* in_sizes, int n_in,
                              void* d_out, int out_size, void* d_ws, size_t ws_size,
                              hipStream_t stream) {
  const float* zd_f = (const float*)d_in[0];
  const float* zt_f = (const float*)d_in[1];
  const int*   row  = (const int*)d_in[2];
  const int*   col  = (const int*)d_in[3];
  const float* W1   = (const float*)d_in[4];
  const float* b1   = (const float*)d_in[5];
  const float* W2   = (const float*)d_in[6];
  const float* b2   = (const float*)d_in[7];
  float* out = (float*)d_out;

  const int E  = in_sizes[2];            // 500000
  const int ND = in_sizes[0] / HDIM;     // 50000
  const int NT = in_sizes[1] / HDIM;     // 20000

  size_t off_w1t = 0;                                    // 256KB
  size_t off_zd  = (size_t)KDIM * HDIM * sizeof(u16);
  size_t off_zt  = off_zd + (size_t)ND * HDIM * sizeof(u16);
  size_t need    = off_zt + (size_t)NT * HDIM * sizeof(u16);  // ~36.1MB

  if (ws_size >= need) {
    u16* w1t = (u16*)((char*)d_ws + off_w1t);
    u16* zdb = (u16*)((char*)d_ws + off_zd);
    u16* ztb = (u16*)((char*)d_ws + off_zt);
    int n4d = ND * HDIM / 4, n4t = NT * HDIM / 4;
    prep_kernel<<<32 + CVT_BLOCKS, 256, 0, stream>>>(zd_f, zt_f, W1,
                                                     zdb, ztb, w1t, n4d, n4t);
    hipMemsetAsync(out, 0, (size_t)E * sizeof(float), stream);
    const int nG = (E + EG - 1) / EG;
    edge_mlp_kernel<<<nG * 2, 256, 0, stream>>>(
        zdb, ztb, row, col, w1t, b1, W2, b2, out, E);
  } else {
    fallback_kernel<<<(E + 15) / 16, 256, 0, stream>>>(
        zd_f, zt_f, row, col, W1, b1, W2, b2, out, E);
  }
}

// Round 9
// 258.735 us; speedup vs baseline: 1.1504x; 1.0633x over previous
//
#include <hip/hip_runtime.h>
#include <hip/hip_bf16.h>
#include <stdint.h>

// EdgeDecoder: out = relu(concat(zd[row], zt[col]) @ W1 + b1) @ W2 + b2
// R11: ALGORITHMIC split. W1 = [W1d; W1t] acts on concat by linearity:
//   U = zd @ W1d (50Kx256), V = zt @ W1t (20Kx256)  -- dense sequential GEMM
//   out[e] = relu(U[row[e]] + V[col[e]] + b1) . W2 + b2  -- pure gather pass
// Kills 93% of FLOPs (131->9.8 GF), all per-edge MFMA/LDS/barriers, and the
// 36MB z-cvt prep. Gather bytes per edge unchanged (1KB, U/V in fp16 to keep
// numerics ~= current bf16 pipeline). R2..R10 showed the fused kernel was
// wall'd by the gather path at ~163us with every schedule; the gather now
// runs barrier-free at max occupancy against L2/L3-resident tables.

typedef unsigned short u16;
typedef __attribute__((ext_vector_type(8))) short short8;
typedef __attribute__((ext_vector_type(4))) float f32x4;

#define HDIM 256
#define KDIM 512
#define BK 64

__device__ __forceinline__ u16 f2bf(float f) {
  union { float f; uint32_t u; } v; v.f = f;
  uint32_t u = v.u;
  return (u16)((u + 0x7fffu + ((u >> 16) & 1u)) >> 16);   // RNE, inputs finite
}
__device__ __forceinline__ u16 f2h(float f) {
  union { _Float16 h; u16 u; } v; v.h = (_Float16)f;      // v_cvt_f16_f32 RNE
  return v.u;
}
__device__ __forceinline__ float h2f(u16 b) {
  union { _Float16 h; u16 u; } v; v.u = b;
  return (float)v.h;
}

// async global->LDS, 16B per lane; LDS dest must be wave-uniform base (+lane*16)
__device__ __forceinline__ void gl2lds16(const void* g, void* l) {
  __builtin_amdgcn_global_load_lds(
      (const __attribute__((address_space(1))) unsigned int*)g,
      (__attribute__((address_space(3))) unsigned int*)l,
      16, 0, 0);
}

// Prep: 64x64 LDS-tiled transpose of W1 (512x256 fp32 -> W1T 256x512 bf16),
// coalesced both sides. 32 blocks, ~3us.
__global__ void prep_w1t(const float* __restrict__ w1, u16* __restrict__ w1t) {
  const int b = blockIdx.x;
  __shared__ float tile[64][65];
  const int k0 = (b >> 2) * 64, n0 = (b & 3) * 64;
  const int tx = threadIdx.x & 63, ty = threadIdx.x >> 6;
#pragma unroll
  for (int i = ty; i < 64; i += 4)
    tile[i][tx] = w1[(size_t)(k0 + i) * HDIM + n0 + tx];
  __syncthreads();
#pragma unroll
  for (int i = ty; i < 64; i += 4)
    w1t[(size_t)(n0 + i) * KDIM + k0 + tx] = f2bf(tile[tx][i]);
}

// UV GEMM: blocks [0,nUb) compute U = zd @ W1d, blocks [nUb,..) V = zt @ W1t.
// Geometry/fragments/swizzle = R10's verified bytes: block = 128 rows x 128
// cols (h-half), 4 waves, wave = 32 rows x 128 cols, acc[2][8]. Rows are
// SEQUENTIAL (no gathers): A read directly from fp32 z (coalesced) and
// converted in-reg (R6's verified cvt pattern). K = 256 -> 4 chunks of BK=64;
// W1T k-chunks kb+kc where kb = 0 (U) or 4 (V). Output stored fp16.
__global__ __launch_bounds__(256, 2) void uv_gemm(
    const float* __restrict__ zdf, const float* __restrict__ ztf,
    const u16* __restrict__ w1t, u16* __restrict__ Uh, u16* __restrict__ Vh,
    int ND, int NT, int nUb) {
  __shared__ u16 lB[2][128 * BK];   // 2 x 16KB [n_local][k], XOR-swizzled

  const int bid = blockIdx.x;
  const int isV = (bid >= nUb);
  const int lb  = isV ? (bid - nUb) : bid;
  const float* zf = isV ? ztf : zdf;
  u16* Oh = isV ? Vh : Uh;
  const int NR = isV ? NT : ND;
  const int r0 = (lb >> 1) * 128;
  const int n0 = (lb & 1) * 128;
  const int kb = isV ? 4 : 0;       // k-chunk base into W1T's 512-k dim

  const int tid   = threadIdx.x;
  const int wid   = tid >> 6;
  const int lane  = tid & 63;
  const int r8    = lane >> 3;
  const int slog  = ((lane & 7) ^ (r8 & 7)) * 8;   // inv-swizzled src piece
  const int colid = lane & 15;
  const int quad  = lane >> 4;
  const int csw   = colid & 7;

  const u16* pB = w1t + (uint32_t)(n0 + wid * 32 + r8) * KDIM + slog;
  u16* lBw0 = &lB[0][(wid * 32) * BK];
  u16* lBw1 = &lB[1][(wid * 32) * BK];

  uint32_t offR[2];
#pragma unroll
  for (int rt = 0; rt < 2; ++rt) {
    int r = min(r0 + wid * 32 + rt * 16 + colid, NR - 1);
    offR[rt] = (uint32_t)r * HDIM;
  }

  f32x4 acc[2][8];
#pragma unroll
  for (int i = 0; i < 2; ++i)
#pragma unroll
    for (int j = 0; j < 8; ++j) acc[i][j] = f32x4{0.f, 0.f, 0.f, 0.f};

  float4 a32[2][2][2][2];  // [buf][rt][s][half] in-flight fp32 A
  short8 aB[2][2][2];      // [buf][rt][s] bf16 fragments

  auto loadA = [&](int kc, int buf) {
#pragma unroll
    for (int rt = 0; rt < 2; ++rt)
#pragma unroll
      for (int s = 0; s < 2; ++s) {
        const float* p = zf + offR[rt] + kc * BK + s * 32 + quad * 8;
        a32[buf][rt][s][0] = ((const float4*)p)[0];
        a32[buf][rt][s][1] = ((const float4*)p)[1];
      }
  };
  auto cvtA = [&](int buf) {
#pragma unroll
    for (int rt = 0; rt < 2; ++rt)
#pragma unroll
      for (int s = 0; s < 2; ++s) {
        float4 lo = a32[buf][rt][s][0], hi = a32[buf][rt][s][1];
        short8 r;
        r[0] = (short)f2bf(lo.x); r[1] = (short)f2bf(lo.y);
        r[2] = (short)f2bf(lo.z); r[3] = (short)f2bf(lo.w);
        r[4] = (short)f2bf(hi.x); r[5] = (short)f2bf(hi.y);
        r[6] = (short)f2bf(hi.z); r[7] = (short)f2bf(hi.w);
        aB[buf][rt][s] = r;
      }
  };
  auto stageB = [&](int kch, u16* dst) {
#pragma unroll
    for (int t = 0; t < 4; ++t)
      gl2lds16(pB + (size_t)t * 8 * KDIM + kch * BK, dst + t * 8 * BK);
  };

  // Prologue
  stageB(kb, lBw0);
  loadA(0, 0);
  asm volatile("s_waitcnt vmcnt(0)" ::: "memory");
  cvtA(0);
  __builtin_amdgcn_s_barrier();

#pragma unroll
  for (int kc = 0; kc < 4; ++kc) {
    const int cur = kc & 1, nxt = cur ^ 1;
    if (kc < 3) {
      stageB(kb + kc + 1, nxt ? lBw1 : lBw0);
      loadA(kc + 1, nxt);
    }
#pragma unroll
    for (int s = 0; s < 2; ++s) {
      const int sl = s * 4 + quad;
      __builtin_amdgcn_s_setprio(1);
#pragma unroll
      for (int ct = 0; ct < 8; ++ct) {
        short8 bF = *(const short8*)
            &lB[cur][(ct * 16 + colid) * BK + ((sl ^ csw) * 8)];
        acc[0][ct] = __builtin_amdgcn_mfma_f32_16x16x32_bf16(
            aB[cur][0][s], bF, acc[0][ct], 0, 0, 0);
        acc[1][ct] = __builtin_amdgcn_mfma_f32_16x16x32_bf16(
            aB[cur][1][s], bF, acc[1][ct], 0, 0, 0);
      }
      __builtin_amdgcn_s_setprio(0);
    }
    if (kc < 3) {
      asm volatile("s_waitcnt vmcnt(0)" ::: "memory");
      cvtA(nxt);
      __builtin_amdgcn_s_barrier();
    }
  }

  // Store fp16 rows. C/D layout: n = n0 + ct*16 + colid,
  // r = r0 + wid*32 + rt*16 + quad*4 + j.
#pragma unroll
  for (int rt = 0; rt < 2; ++rt)
#pragma unroll
    for (int j = 0; j < 4; ++j) {
      int r = r0 + wid * 32 + rt * 16 + quad * 4 + j;
      if (r < NR) {
#pragma unroll
        for (int ct = 0; ct < 8; ++ct)
          Oh[(size_t)r * HDIM + n0 + ct * 16 + colid] = f2h(acc[rt][ct][j]);
      }
    }
}

// Edge pass: pure streaming gather. 8 lanes per edge; lane li owns cols
// [li*32, +32) (fp16, 4x16B contiguous loads per table). No LDS, no barriers.
__global__ __launch_bounds__(256, 4) void edge_kernel(
    const u16* __restrict__ U, const u16* __restrict__ V,
    const int* __restrict__ row, const int* __restrict__ col,
    const float* __restrict__ b1, const float* __restrict__ w2,
    const float* __restrict__ b2, float* __restrict__ out, int E) {
  const int tid  = threadIdx.x;
  const int lane = tid & 63;
  const int wid  = tid >> 6;
  const int li   = lane & 7;        // lane-in-edge
  const int eg   = lane >> 3;       // edge-in-wave (0..7)

  float b1v[32], w2v[32];
#pragma unroll
  for (int i = 0; i < 32; ++i) {
    b1v[i] = b1[li * 32 + i];
    w2v[i] = w2[li * 32 + i];
  }
  const float b2v = b2[0];

  for (int base = blockIdx.x * 32; base < E; base += gridDim.x * 32) {
    const int e  = base + wid * 8 + eg;
    const int ee = min(e, E - 1);
    const short8* up = (const short8*)(U + (size_t)row[ee] * HDIM + li * 32);
    const short8* vp = (const short8*)(V + (size_t)col[ee] * HDIM + li * 32);
    short8 ub[4], vb[4];
#pragma unroll
    for (int t = 0; t < 4; ++t) { ub[t] = up[t]; vb[t] = vp[t]; }
    float s = 0.f;
#pragma unroll
    for (int t = 0; t < 4; ++t)
#pragma unroll
      for (int i = 0; i < 8; ++i) {
        float h = h2f((u16)ub[t][i]) + h2f((u16)vb[t][i]) + b1v[t * 8 + i];
        s += fmaxf(h, 0.f) * w2v[t * 8 + i];
      }
    s += __shfl_xor(s, 1, 8);
    s += __shfl_xor(s, 2, 8);
    s += __shfl_xor(s, 4, 8);
    if (li == 0 && e < E) out[e] = s + b2v;
  }
}

// Correct-but-slow fp32 fallback (only if ws too small): 16 edges/block.
__global__ void fallback_kernel(
    const float* __restrict__ zd, const float* __restrict__ zt,
    const int* __restrict__ row, const int* __restrict__ col,
    const float* __restrict__ W1, const float* __restrict__ b1,
    const float* __restrict__ W2, const float* __restrict__ b2,
    float* __restrict__ out, int E) {
  __shared__ float zc[16][512];
  __shared__ float red[4][16];
  const int e0 = blockIdx.x * 16;
  const int tid = threadIdx.x;
  for (int i = tid; i < 16 * 512; i += 256) {
    int e = i >> 9, k = i & 511;
    int ge = min(e0 + e, E - 1);
    zc[e][k] = (k < HDIM) ? zd[(size_t)row[ge] * HDIM + k]
                          : zt[(size_t)col[ge] * HDIM + (k - HDIM)];
  }
  __syncthreads();
  float acc[16];
#pragma unroll
  for (int e = 0; e < 16; ++e) acc[e] = 0.f;
  for (int k = 0; k < KDIM; ++k) {
    float w = W1[k * HDIM + tid];
#pragma unroll
    for (int e = 0; e < 16; ++e) acc[e] += zc[e][k] * w;
  }
  float wv = W2[tid], bv = b1[tid];
  const int lane = tid & 63, wid = tid >> 6;
#pragma unroll
  for (int e = 0; e < 16; ++e) {
    float pv = fmaxf(acc[e] + bv, 0.f) * wv;
#pragma unroll
    for (int off = 32; off >= 1; off >>= 1) pv += __shfl_down(pv, off, 64);
    if (lane == 0) red[wid][e] = pv;
  }
  __syncthreads();
  if (tid < 16) {
    int ge = e0 + tid;
    if (ge < E)
      out[ge] = red[0][tid] + red[1][tid] + red[2][tid] + red[3][tid] + b2[0];
  }
}

extern "C" void kernel_launch(void* const* d_in, const int* in_sizes, int n_in,
                              void* d_out, int out_size, void* d_ws, size_t ws_size,
                              hipStream_t stream) {
  const float* zd_f = (const float*)d_in[0];
  const float* zt_f = (const float*)d_in[1];
  const int*   row  = (const int*)d_in[2];
  const int*   col  = (const int*)d_in[3];
  const float* W1   = (const float*)d_in[4];
  const float* b1   = (const float*)d_in[5];
  const float* W2   = (const float*)d_in[6];
  const float* b2   = (const float*)d_in[7];
  float* out = (float*)d_out;

  const int E  = in_sizes[2];            // 500000
  const int ND = in_sizes[0] / HDIM;     // 50000
  const int NT = in_sizes[1] / HDIM;     // 20000

  size_t off_w1t = 0;                                        // 256KB
  size_t off_U   = (size_t)KDIM * HDIM * sizeof(u16);
  size_t off_V   = off_U + (size_t)ND * HDIM * sizeof(u16);  // U: 25.6MB
  size_t need    = off_V + (size_t)NT * HDIM * sizeof(u16);  // ~36.1MB

  if (ws_size >= need) {
    u16* w1t = (u16*)((char*)d_ws + off_w1t);
    u16* Uh  = (u16*)((char*)d_ws + off_U);
    u16* Vh  = (u16*)((char*)d_ws + off_V);
    const int nUb = ((ND + 127) / 128) * 2;    // 782
    const int nVb = ((NT + 127) / 128) * 2;    // 314
    prep_w1t<<<32, 256, 0, stream>>>(W1, w1t);
    uv_gemm<<<nUb + nVb, 256, 0, stream>>>(zd_f, zt_f, w1t, Uh, Vh,
                                           ND, NT, nUb);
    int egrid = (E + 31) / 32;
    if (egrid > 2048) egrid = 2048;
    edge_kernel<<<egrid, 256, 0, stream>>>(Uh, Vh, row, col, b1, W2, b2,
                                           out, E);
  } else {
    fallback_kernel<<<(E + 15) / 16, 256, 0, stream>>>(
        zd_f, zt_f, row, col, W1, b1, W2, b2, out, E);
  }
}